// Round 4
// baseline (241.257 us; speedup 1.0000x reference)
//
#include <hip/hip_runtime.h>
#include <hip/hip_cooperative_groups.h>
#include <stdint.h>

namespace cg = cooperative_groups;

#define NQ   8192
#define NB   2
#define KNN  10
#define K1   11                 // top-11 incl. self (d=0); self dropped in loss
#define NTOT (NB * NQ)
#define NGRP (NTOT / 64)        // 256 blocks, 1/CU (cooperative co-residency)
#define IDXMASK 0x1FFFu

// x-bucketing
#define NBUK 2048
#define XMIN (-6.0f)
#define XRANGE 12.0f

// tau: upper bound via 11th-smallest of block-minima over a 2048-point subsample
#define TW   16                 // 16 waves (1024 threads)
#define MSUB 2048
#define SSTR (NQ / MSUB)        // 4
#define TB   8                  // minima blocks per (wave,lane)
#define TI   16                 // samples per minima block (x-decorrelated stride-16)

// windowed scan
#define WCHUNK 2048             // 32 KB float4 chunk
#define CAP    17               // private list per (wave,lane); lambda~3.3 -> P(ovf) tiny; odd stride
#define CKI(s, c, lane) (((s) * TW + (c)) * 64 + (lane))

static __device__ __forceinline__ uint32_t umin32(uint32_t a, uint32_t b) { return a < b ? a : b; }
static __device__ __forceinline__ uint32_t umax32(uint32_t a, uint32_t b) { return a > b ? a : b; }

static __device__ __forceinline__ void insert11(uint32_t (&l)[K1], uint32_t key) {
#pragma unroll
    for (int s = 0; s < K1; ++s) {
        const uint32_t m = l[s];
        l[s] = umin32(key, m);
        key  = umax32(key, m);
    }
}

// ---------------- single cooperative kernel: sort -> tau -> scan -> merge -> loss ----------------
__global__ __launch_bounds__(1024, 1) void plap_all(
    const float* __restrict__ p1, const float* __restrict__ p2,
    float4* __restrict__ srt, uint32_t* __restrict__ boff,
    uint32_t* __restrict__ hist, uint32_t* __restrict__ cur,
    float* __restrict__ out)
{
    __shared__ __align__(16) float4 win[WCHUNK];       // 32 KB: scan scratch / subsample / chunks
    __shared__ uint32_t ckls[TW * 64 * CAP];           // 68 KB: lists + tree-merge scratch (aliased)
    __shared__ float    tauF[64];                      // total ~102.6 KB -> 1 block/CU

    cg::grid_group grid = cg::this_grid();
    const int tid  = threadIdx.x;
    const int gtid = blockIdx.x * 1024 + tid;

    // ---- phase 0: zero counters + output; load my point & bucket ----
    if (gtid < NB * NBUK) hist[gtid] = 0u;
    if (gtid == 0) out[0] = 0.0f;
    float px = 0.f, py = 0.f, pz = 0.f; int bb = 0, pb = 0;
    if (gtid < NTOT) {
        pb = gtid >> 13;
        const int idx = gtid & (NQ - 1);
        const float* src = p1 + ((size_t)pb * NQ + idx) * 3;
        px = src[0]; py = src[1]; pz = src[2];
        int t = (int)floorf((px - XMIN) * ((float)NBUK / XRANGE));
        bb = t < 0 ? 0 : (t > NBUK - 1 ? NBUK - 1 : t);
    }
    grid.sync();

    // ---- phase 1: global histogram ----
    if (gtid < NTOT) atomicAdd(&hist[pb * NBUK + bb], 1u);
    grid.sync();

    // ---- phase 2: prefix scan (block b < NB handles batch b) ----
    if (blockIdx.x < NB) {
        uint32_t* h0 = (uint32_t*)win;                 // 8 KB
        uint32_t* h1 = h0 + NBUK;                      // 8 KB (within win's 32 KB)
        const uint32_t* H = hist + blockIdx.x * NBUK;
        for (int i = tid; i < NBUK; i += 1024) h0[i] = H[i];
        __syncthreads();
        uint32_t* s0 = h0; uint32_t* s1 = h1;
        for (int s = 1; s < NBUK; s <<= 1) {
            for (int i = tid; i < NBUK; i += 1024)
                s1[i] = s0[i] + (i >= s ? s0[i - s] : 0u);
            __syncthreads();
            uint32_t* tm = s0; s0 = s1; s1 = tm;
        }
        uint32_t* BO = boff + blockIdx.x * (NBUK + 1);
        uint32_t* CU = cur  + blockIdx.x * NBUK;
        for (int i = tid; i < NBUK; i += 1024) {
            BO[i + 1] = s0[i];
            CU[i]     = (i == 0) ? 0u : s0[i - 1];     // exclusive cursors
        }
        if (tid == 0) BO[0] = 0u;
    }
    grid.sync();

    // ---- phase 3: scatter into sorted order (payload .w = original index) ----
    if (gtid < NTOT) {
        const uint32_t pos = atomicAdd(&cur[pb * NBUK + bb], 1u);
        srt[(size_t)pb * NQ + pos] =
            make_float4(px, py, pz, __uint_as_float((uint32_t)(gtid & (NQ - 1))));
    }
    grid.sync();

    // ================= fused per-group phase =================
    const int lane = tid & 63;
    const int wave = tid >> 6;
    const int wq   = __builtin_amdgcn_readfirstlane(wave);
    const int b    = blockIdx.x >> 7;
    const int q0   = (blockIdx.x & 127) << 6;
    const float4*   __restrict__ S  = srt  + (size_t)b * NQ;
    const uint32_t* __restrict__ BO = boff + (size_t)b * (NBUK + 1);
    const float*    __restrict__ P1 = p1 + (size_t)b * NQ * 3;
    const float*    __restrict__ P2 = p2 + (size_t)b * NQ * 3;

    const float4 Q = S[q0 + lane];
    const float qx = Q.x, qy = Q.y, qz = Q.z;
    const uint32_t qidO = __float_as_uint(Q.w);

    // stage 2048-point subsample (stride 4 of sorted) into win
    __syncthreads();                                   // phase-2 scratch users done
    for (int i = tid; i < MSUB; i += 1024) win[i] = S[i * SSTR];
    __syncthreads();

    // ---- tau: 8 block-minima of 16 x-decorrelated samples, insert, tree-merge ----
    {
        uint32_t l[K1];
#pragma unroll
        for (int s = 0; s < K1; ++s) l[s] = 0xFFFFFFFFu;
#pragma unroll
        for (int o = 0; o < TB; ++o) {
            float m = 1e30f;
#pragma unroll
            for (int i = 0; i < TI; ++i) {
                const float4 C = win[wq + (o << 8) + (i << 4)];   // broadcast ds_read_b128
                const float dx = qx - C.x, dy = qy - C.y, dz = qz - C.z;
                m = fminf(m, fmaf(dx, dx, fmaf(dy, dy, dz * dz)));
            }
            insert11(l, __float_as_uint(m));           // min is an actual sample distance
        }
#pragma unroll
        for (int s = 0; s < K1; ++s) ckls[CKI(s, wq, lane)] = l[s];
        for (int st = 1; st < TW; st <<= 1) {          // 11th of 128 block-minima >= d11
            __syncthreads();
            if ((wq & (2 * st - 1)) == 0) {
#pragma unroll
                for (int e = 0; e < K1; ++e) insert11(l, ckls[CKI(e, wq + st, lane)]);
                if (2 * st < TW) {
#pragma unroll
                    for (int s = 0; s < K1; ++s) ckls[CKI(s, wq, lane)] = l[s];
                } else {
                    tauF[lane] = __uint_as_float(l[K1 - 1] | IDXMASK);
                }
            }
        }
        __syncthreads();
    }

    const float tauUpF = tauF[lane];                   // trunc-space superset bound
    // block union window in x (exact superset; +ulp guard on sqrt)
    const float sL = sqrtf(tauUpF) * 1.0001f;
    float smax = sL, xmn = qx, xmx = qx;
#pragma unroll
    for (int off = 32; off > 0; off >>= 1) {
        smax = fmaxf(smax, __shfl_xor(smax, off, 64));
        xmn  = fminf(xmn,  __shfl_xor(xmn,  off, 64));
        xmx  = fmaxf(xmx,  __shfl_xor(xmx,  off, 64));
    }
    const float scale = (float)NBUK / XRANGE;
    int blo = (int)floorf((xmn - smax - XMIN) * scale);
    int bhi = (int)floorf((xmx + smax - XMIN) * scale);
    blo = blo < 0 ? 0 : (blo > NBUK - 1 ? NBUK - 1 : blo);
    bhi = bhi < 0 ? 0 : (bhi > NBUK - 1 ? NBUK - 1 : bhi);
    const uint32_t wlo = BO[blo];
    const uint32_t whi = BO[bhi + 1];

    // ---- chunked window scan: private lists, sentinel-padded, unroll 4 ----
    uint32_t F[K1];
#pragma unroll
    for (int s = 0; s < K1; ++s) F[s] = 0xFFFFFFFFu;
    const uint32_t lbase = (uint32_t)(wq * 64 + lane) * CAP;

    for (uint32_t cb = wlo; cb < whi; cb += WCHUNK) {
        const int n    = (int)umin32(whi - cb, WCHUNK);
        const int npad = (n + 63) & ~63;               // multiple of 64 -> iters%4==0
        __syncthreads();                               // prev chunk fully consumed
        for (int i = tid; i < npad; i += 1024)
            win[i] = (i < n) ? S[cb + i] : make_float4(1e19f, 1e19f, 1e19f, 0.f);
        __syncthreads();

        uint32_t cnt = 0;
        const int iters = npad >> 4;
        __builtin_assume(iters % 4 == 0);
#pragma unroll 4
        for (int t = 0; t < iters; ++t) {
            const float4 C = win[(t << 4) | wq];       // broadcast ds_read_b128
            const float dx = qx - C.x, dy = qy - C.y, dz = qz - C.z;
            const float d  = fmaf(dx, dx, fmaf(dy, dy, dz * dz));
            if (d <= tauUpF) {
                const uint32_t key = (__float_as_uint(d) & ~IDXMASK)
                                   | (__float_as_uint(C.w) & IDXMASK);
                if (cnt < CAP) ckls[lbase + cnt] = key;
                ++cnt;
            }
        }
        if (cnt <= CAP) {                              // drain own list into regs
            for (uint32_t s = 0; s < cnt; ++s) insert11(F, ckls[lbase + s]);
        } else {                                       // exact fallback: rescan own share
            for (int t = 0; t < iters; ++t) {
                const float4 C = win[(t << 4) | wq];
                const float dx = qx - C.x, dy = qy - C.y, dz = qz - C.z;
                const float d  = fmaf(dx, dx, fmaf(dy, dy, dz * dz));
                if (d <= tauUpF)
                    insert11(F, (__float_as_uint(d) & ~IDXMASK)
                              | (__float_as_uint(C.w) & IDXMASK));
            }
        }
    }
    __syncthreads();                                   // all drains done before scratch reuse

    // ---- tree merge 16 -> 1 ----
#pragma unroll
    for (int s = 0; s < K1; ++s) ckls[CKI(s, wq, lane)] = F[s];
    for (int st = 1; st < TW; st <<= 1) {
        __syncthreads();
        if ((wq & (2 * st - 1)) == 0) {
#pragma unroll
            for (int e = 0; e < K1; ++e) insert11(F, ckls[CKI(e, wq + st, lane)]);
            if (2 * st < TW) {
#pragma unroll
                for (int s = 0; s < K1; ++s) ckls[CKI(s, wq, lane)] = F[s];
            }
        }
    }

    // ---- loss: wave 0, lane = query (neighbor indices are ORIGINAL indices) ----
    if (wq == 0) {
        float s1x = 0.f, s1y = 0.f, s1z = 0.f, s2x = 0.f, s2y = 0.f, s2z = 0.f;
#pragma unroll
        for (int s = 1; s < K1; ++s) {                 // F[0] = self (trunc d = 0)
            const int n = (int)(F[s] & IDXMASK);
            s1x += P1[n * 3 + 0]; s1y += P1[n * 3 + 1]; s1z += P1[n * 3 + 2];
            s2x += P2[n * 3 + 0]; s2y += P2[n * 3 + 1]; s2z += P2[n * 3 + 2];
        }
        const float invk = 1.0f / (float)KNN;
        const float lx = (s1x * invk - qx) - (s2x * invk - P2[qidO * 3 + 0]);
        const float ly = (s1y * invk - qy) - (s2y * invk - P2[qidO * 3 + 1]);
        const float lz = (s1z * invk - qz) - (s2z * invk - P2[qidO * 3 + 2]);
        float acc = fabsf(lx) + fabsf(ly) + fabsf(lz);
#pragma unroll
        for (int off = 32; off > 0; off >>= 1)
            acc += __shfl_down(acc, off, 64);
        if (lane == 0) atomicAdd(out, acc * (1.0f / (float)(NTOT * 3)));
    }
}

extern "C" void kernel_launch(void* const* d_in, const int* in_sizes, int n_in,
                              void* d_out, int out_size, void* d_ws, size_t ws_size,
                              hipStream_t stream) {
    const float* p1 = (const float*)d_in[0];
    const float* p2 = (const float*)d_in[1];
    float* out      = (float*)d_out;

    // ws: sorted float4 (256 KB) | boff | hist | cur
    float4*   srt  = (float4*)d_ws;
    uint32_t* boff = (uint32_t*)(srt + (size_t)NB * NQ);
    uint32_t* hist = boff + (size_t)NB * (NBUK + 1);
    uint32_t* cur  = hist + (size_t)NB * NBUK;

    void* args[] = {(void*)&p1, (void*)&p2, (void*)&srt, (void*)&boff,
                    (void*)&hist, (void*)&cur, (void*)&out};
    hipLaunchCooperativeKernel((const void*)plap_all, dim3(NGRP), dim3(1024),
                               args, 0, stream);
}

// Round 5
// 156.442 us; speedup vs baseline: 1.5421x; 1.5421x over previous
//
#include <hip/hip_runtime.h>
#include <stdint.h>

#define NQ   8192
#define NB   2
#define KNN  10
#define K1   11                 // top-11 incl. self (d=0); self dropped in loss
#define NTOT (NB * NQ)
#define NGRP (NTOT / 64)        // 256 blocks of 64 sorted queries, 1/CU
#define IDXMASK 0x1FFFu

// x-bucketing
#define NBUK  2048
#define XMIN  (-6.0f)
#define XRANGE 12.0f
#define BSCALE ((float)NBUK / XRANGE)

// tau: exact 11th-smallest over a 1024-point subsample = 64 runs of 16 consecutive
// sorted points (run stride 128 positions) -> coalesced staging, spread in x
#define TW   16                 // 16 waves (1024 threads)
#define CKI(s, c, lane) (((s) * TW + (c)) * 64 + (lane))

// windowed scan
#define WCHUNK 2048             // 32 KB float4 chunk
#define CAP    16               // private self-draining list per (wave,lane)
#define LSTR   17               // odd stride -> conflict-free

static __device__ __forceinline__ uint32_t umin32(uint32_t a, uint32_t b) { return a < b ? a : b; }
static __device__ __forceinline__ uint32_t umax32(uint32_t a, uint32_t b) { return a > b ? a : b; }

static __device__ __forceinline__ void insert11(uint32_t (&l)[K1], uint32_t key) {
#pragma unroll
    for (int s = 0; s < K1; ++s) {
        const uint32_t m = l[s];
        l[s] = umin32(key, m);
        key  = umax32(key, m);
    }
}

// ---------------- k1: histogram (16 blocks, LDS-aggregated); zeroes out[0] ----------------
__global__ __launch_bounds__(1024) void k_hist(
    const float* __restrict__ p1, uint32_t* __restrict__ hist, float* __restrict__ out)
{
    __shared__ uint32_t lh[NBUK];
    const int tid  = threadIdx.x;
    const int gtid = blockIdx.x * 1024 + tid;
    if (gtid == 0) out[0] = 0.0f;
    lh[tid] = 0u; lh[tid + 1024] = 0u;
    __syncthreads();
    const int pb  = gtid >> 13;                        // whole block is one batch (8 blocks/batch)
    const int idx = gtid & (NQ - 1);
    const float x = p1[((size_t)pb * NQ + idx) * 3];
    int bb = (int)floorf((x - XMIN) * BSCALE);
    bb = bb < 0 ? 0 : (bb > NBUK - 1 ? NBUK - 1 : bb);
    atomicAdd(&lh[bb], 1u);
    __syncthreads();
    uint32_t v;
    if ((v = lh[tid]))        atomicAdd(&hist[pb * NBUK + tid], v);
    if ((v = lh[tid + 1024])) atomicAdd(&hist[pb * NBUK + tid + 1024], v);
}

// ---------------- k2: prefix scan -> bucket offsets + scatter cursors (2 blocks) ----------------
__global__ __launch_bounds__(1024) void k_scan(
    const uint32_t* __restrict__ hist, uint32_t* __restrict__ boff, uint32_t* __restrict__ cur)
{
    __shared__ uint32_t h0[NBUK], h1[NBUK];
    const int tid = threadIdx.x;
    const int b   = blockIdx.x;
    const uint32_t* H = hist + (size_t)b * NBUK;
    for (int i = tid; i < NBUK; i += 1024) h0[i] = H[i];
    __syncthreads();
    uint32_t* s0 = h0; uint32_t* s1 = h1;
    for (int s = 1; s < NBUK; s <<= 1) {
        for (int i = tid; i < NBUK; i += 1024)
            s1[i] = s0[i] + (i >= s ? s0[i - s] : 0u);
        __syncthreads();
        uint32_t* t = s0; s0 = s1; s1 = t;
    }
    uint32_t* BO = boff + (size_t)b * (NBUK + 1);
    uint32_t* CU = cur  + (size_t)b * NBUK;
    for (int i = tid; i < NBUK; i += 1024) {
        BO[i + 1] = s0[i];
        CU[i]     = (i == 0) ? 0u : s0[i - 1];
    }
    if (tid == 0) BO[0] = 0u;
}

// ---------------- k3: scatter into sorted order (16 blocks) ----------------
__global__ __launch_bounds__(1024) void k_scatter(
    const float* __restrict__ p1, uint32_t* __restrict__ cur, float4* __restrict__ srt)
{
    const int tid  = threadIdx.x;
    const int gtid = blockIdx.x * 1024 + tid;
    const int pb   = gtid >> 13;
    const int idx  = gtid & (NQ - 1);
    const float* src = p1 + ((size_t)pb * NQ + idx) * 3;
    const float x = src[0], y = src[1], z = src[2];
    int bb = (int)floorf((x - XMIN) * BSCALE);
    bb = bb < 0 ? 0 : (bb > NBUK - 1 ? NBUK - 1 : bb);
    const uint32_t pos = atomicAdd(&cur[pb * NBUK + bb], 1u);
    srt[(size_t)pb * NQ + pos] = make_float4(x, y, z, __uint_as_float((uint32_t)idx));
}

// ---------------- k4: fused tau -> windowed scan -> merge -> loss ----------------
__global__ __launch_bounds__(1024, 1) void k_fused(
    const float4* __restrict__ srt, const uint32_t* __restrict__ boff,
    const float* __restrict__ p1, const float* __restrict__ p2,
    float* __restrict__ out)
{
    __shared__ __align__(16) float4 win[WCHUNK];       // 32 KB: subsample / chunks / loss scratch
    __shared__ uint32_t ckls[TW * 64 * K1];            // 44 KB: tau + final tree-merge scratch
    __shared__ uint32_t lists[TW * 64 * LSTR];         // 68 KB: private survivor lists
    __shared__ float    tauF[64];                      // total ~148 KB -> 1 block/CU

    const int tid  = threadIdx.x;
    const int lane = tid & 63;
    const int wave = tid >> 6;
    const int wq   = __builtin_amdgcn_readfirstlane(wave);
    const int b    = blockIdx.x >> 7;
    const int q0   = (blockIdx.x & 127) << 6;
    const float4*   __restrict__ S  = srt  + (size_t)b * NQ;
    const uint32_t* __restrict__ BO = boff + (size_t)b * (NBUK + 1);
    const float*    __restrict__ P1 = p1 + (size_t)b * NQ * 3;
    const float*    __restrict__ P2 = p2 + (size_t)b * NQ * 3;

    const float4 Q = S[q0 + lane];                     // my query (payload .w = original idx)
    const float qx = Q.x, qy = Q.y, qz = Q.z;
    const uint32_t qidO = __float_as_uint(Q.w);

    // ---- stage 1024-sample subsample: 64 runs of 16 consecutive (coalesced 256-B bursts) ----
    win[tid & 1023] = S[((tid & 1023) >> 4) * 128 + (tid & 15)];
    __syncthreads();

    // ---- tau: exact top-11 of 1024 samples; per (wave,lane) 4 runs x 16, tree-merge 16->1 ----
    uint32_t F[K1];
    {
        uint32_t l[K1];
#pragma unroll
        for (int s = 0; s < K1; ++s) l[s] = 0xFFFFFFFFu;
#pragma unroll
        for (int o = 0; o < 4; ++o) {
            const int base = (((o << 4) | wq) << 4);   // run (o*16+wq), 16 entries
#pragma unroll 4
            for (int i = 0; i < 16; ++i) {
                const float4 C = win[base + i];        // broadcast ds_read_b128
                const float dx = qx - C.x, dy = qy - C.y, dz = qz - C.z;
                const float d  = fmaf(dx, dx, fmaf(dy, dy, dz * dz));
                insert11(l, __float_as_uint(d));
            }
        }
#pragma unroll
        for (int s = 0; s < K1; ++s) ckls[CKI(s, wq, lane)] = l[s];
        for (int st = 1; st < TW; st <<= 1) {
            __syncthreads();
            if ((wq & (2 * st - 1)) == 0) {
#pragma unroll
                for (int e = 0; e < K1; ++e) insert11(l, ckls[CKI(e, wq + st, lane)]);
                if (2 * st < TW) {
#pragma unroll
                    for (int s = 0; s < K1; ++s) ckls[CKI(s, wq, lane)] = l[s];
                } else {
                    tauF[lane] = __uint_as_float(l[K1 - 1] | IDXMASK);
                }
            }
        }
        __syncthreads();
    }

    const float tauUpF = tauF[lane];                   // trunc-space superset bound
    // ---- block union window in x (exact superset; +ulp guard on sqrt) ----
    const float sL = sqrtf(tauUpF) * 1.0001f;
    float smax = sL, xmn = qx, xmx = qx;
#pragma unroll
    for (int off = 32; off > 0; off >>= 1) {
        smax = fmaxf(smax, __shfl_xor(smax, off, 64));
        xmn  = fminf(xmn,  __shfl_xor(xmn,  off, 64));
        xmx  = fmaxf(xmx,  __shfl_xor(xmx,  off, 64));
    }
    int blo = (int)floorf((xmn - smax - XMIN) * BSCALE);
    int bhi = (int)floorf((xmx + smax - XMIN) * BSCALE);
    blo = blo < 0 ? 0 : (blo > NBUK - 1 ? NBUK - 1 : blo);
    bhi = bhi < 0 ? 0 : (bhi > NBUK - 1 ? NBUK - 1 : bhi);
    const uint32_t wlo = BO[blo];
    const uint32_t whi = BO[bhi + 1];

    // ---- chunked window scan: self-draining private lists (exact, no overflow path) ----
#pragma unroll
    for (int s = 0; s < K1; ++s) F[s] = 0xFFFFFFFFu;
    const uint32_t lbase = (uint32_t)(wq * 64 + lane) * LSTR;
    uint32_t cnt = 0;

    for (uint32_t cb = wlo; cb < whi; cb += WCHUNK) {
        const int n    = (int)umin32(whi - cb, WCHUNK);
        const int npad = (n + 63) & ~63;               // multiple of 64 -> iters%4==0
        __syncthreads();                               // prev chunk / subsample consumed
        for (int i = tid; i < npad; i += 1024)
            win[i] = (i < n) ? S[cb + i] : make_float4(1e19f, 1e19f, 1e19f, 0.f);
        __syncthreads();

        const int iters = npad >> 4;
        __builtin_assume(iters % 4 == 0);
#pragma unroll 4
        for (int t = 0; t < iters; ++t) {
            const float4 C = win[(t << 4) | wq];       // broadcast ds_read_b128
            const float dx = qx - C.x, dy = qy - C.y, dz = qz - C.z;
            const float d  = fmaf(dx, dx, fmaf(dy, dy, dz * dz));
            if (d <= tauUpF) {
                lists[lbase + cnt] = (__float_as_uint(d) & ~IDXMASK)
                                   | (__float_as_uint(C.w) & IDXMASK);
                if (++cnt == CAP) {                    // rare (P ~ 1e-4/lane): drain to regs
#pragma unroll
                    for (int s2 = 0; s2 < CAP; ++s2) insert11(F, lists[lbase + s2]);
                    cnt = 0;
                }
            }
        }
    }
    for (uint32_t s = 0; s < cnt; ++s) insert11(F, lists[lbase + s]);   // final drain
    __syncthreads();                                   // all win/ckls readers done

    // ---- tree merge 16 -> 1 ----
#pragma unroll
    for (int s = 0; s < K1; ++s) ckls[CKI(s, wq, lane)] = F[s];
    for (int st = 1; st < TW; st <<= 1) {
        __syncthreads();
        if ((wq & (2 * st - 1)) == 0) {
#pragma unroll
            for (int e = 0; e < K1; ++e) insert11(F, ckls[CKI(e, wq + st, lane)]);
            if (2 * st < TW) {
#pragma unroll
                for (int s = 0; s < K1; ++s) ckls[CKI(s, wq, lane)] = F[s];
            }
        }
    }
    __syncthreads();                                   // tree reads done; win reusable

    // ---- parallel loss: 10 waves gather neighbors concurrently, LDS float accumulate ----
    uint32_t* nIdx = (uint32_t*)win;                   // [10][64]
    float*    sums = (float*)win + 640;                // [6][64]: s1x s1y s1z s2x s2y s2z
    if (tid < 384) sums[tid] = 0.0f;
    if (wq == 0) {
#pragma unroll
        for (int s = 1; s < K1; ++s)                   // F[0] = self (trunc d = 0)
            nIdx[(s - 1) * 64 + lane] = F[s] & IDXMASK;
    }
    __syncthreads();
    if (wq < 10) {
        const int n = (int)nIdx[wq * 64 + lane];
        atomicAdd(&sums[0 * 64 + lane], P1[n * 3 + 0]);
        atomicAdd(&sums[1 * 64 + lane], P1[n * 3 + 1]);
        atomicAdd(&sums[2 * 64 + lane], P1[n * 3 + 2]);
        atomicAdd(&sums[3 * 64 + lane], P2[n * 3 + 0]);
        atomicAdd(&sums[4 * 64 + lane], P2[n * 3 + 1]);
        atomicAdd(&sums[5 * 64 + lane], P2[n * 3 + 2]);
    }
    __syncthreads();
    if (wq == 0) {
        const float invk = 1.0f / (float)KNN;
        const float lx = (sums[0 * 64 + lane] * invk - qx) - (sums[3 * 64 + lane] * invk - P2[qidO * 3 + 0]);
        const float ly = (sums[1 * 64 + lane] * invk - qy) - (sums[4 * 64 + lane] * invk - P2[qidO * 3 + 1]);
        const float lz = (sums[2 * 64 + lane] * invk - qz) - (sums[5 * 64 + lane] * invk - P2[qidO * 3 + 2]);
        float acc = fabsf(lx) + fabsf(ly) + fabsf(lz);
#pragma unroll
        for (int off = 32; off > 0; off >>= 1)
            acc += __shfl_down(acc, off, 64);
        if (lane == 0) atomicAdd(out, acc * (1.0f / (float)(NTOT * 3)));
    }
}

extern "C" void kernel_launch(void* const* d_in, const int* in_sizes, int n_in,
                              void* d_out, int out_size, void* d_ws, size_t ws_size,
                              hipStream_t stream) {
    const float* p1 = (const float*)d_in[0];
    const float* p2 = (const float*)d_in[1];
    float* out      = (float*)d_out;

    // ws: srt (256 KB) | boff (16.4 KB) | hist (16 KB) | cur (16 KB)
    float4*   srt  = (float4*)d_ws;
    uint32_t* boff = (uint32_t*)(srt + (size_t)NB * NQ);
    uint32_t* hist = boff + (size_t)NB * (NBUK + 1);
    uint32_t* cur  = hist + (size_t)NB * NBUK;

    hipMemsetAsync(hist, 0, (size_t)NB * NBUK * sizeof(uint32_t), stream);
    k_hist   <<<dim3(16),   dim3(1024), 0, stream>>>(p1, hist, out);
    k_scan   <<<dim3(NB),   dim3(1024), 0, stream>>>(hist, boff, cur);
    k_scatter<<<dim3(16),   dim3(1024), 0, stream>>>(p1, cur, srt);
    k_fused  <<<dim3(NGRP), dim3(1024), 0, stream>>>(srt, boff, p1, p2, out);
}